// Round 9
// baseline (154.289 us; speedup 1.0000x reference)
//
#include <hip/hip_runtime.h>
#include <hip/hip_bf16.h>

#define B_ 128
#define T_ 256
#define D_ 1024
#define L_ 48
#define SMALL_ (-1000.0f)

typedef float f32x4 __attribute__((ext_vector_type(4)));
typedef short bf16x8 __attribute__((ext_vector_type(8)));
typedef short bf16x4 __attribute__((ext_vector_type(4)));
typedef unsigned u32x4 __attribute__((ext_vector_type(4)));
typedef unsigned u32x2 __attribute__((ext_vector_type(2)));

__device__ __forceinline__ float bcastf(float v, int lane) {
    return __uint_as_float(__builtin_amdgcn_readlane(__float_as_uint(v), lane));
}
__device__ __forceinline__ unsigned cvt_pk_bf16(float lo, float hi) {
    unsigned r;
    asm("v_cvt_pk_bf16_f32 %0, %1, %2" : "=v"(r) : "v"(lo), "v"(hi));
    return r;
}
__device__ __forceinline__ bf16x4 pack4(float a, float b, float c, float d) {
    u32x2 u = {cvt_pk_bf16(a, b), cvt_pk_bf16(c, d)};
    return __builtin_bit_cast(bf16x4, u);
}
__device__ __forceinline__ f32x4 mfma16(bf16x4 a, bf16x4 b, f32x4 c) {
#if __has_builtin(__builtin_amdgcn_mfma_f32_16x16x16bf16_1k)
    return __builtin_amdgcn_mfma_f32_16x16x16bf16_1k(a, b, c, 0, 0, 0);
#else
    asm volatile("v_mfma_f32_16x16x16_bf16 %0, %1, %2, %0" : "+v"(c) : "v"(a), "v"(b));
    return c;
#endif
}
__device__ __forceinline__ unsigned short f2bfu(float f) {
    unsigned u = __float_as_uint(f);
    return (unsigned short)((u + 0x7FFFu + ((u >> 16) & 1u)) >> 16);
}

// ---------- Kernel 1: W -> bf16, E^T -> bf16, zero tickets ----------
__global__ __launch_bounds__(256) void prep_kernel(const float* __restrict__ W,
                                                   const float* __restrict__ trans,
                                                   unsigned short* __restrict__ wbf,
                                                   unsigned short* __restrict__ etbf,
                                                   unsigned* __restrict__ tickets) {
    int i = blockIdx.x * 256 + threadIdx.x;   // 49152 total
    if (i < 129) tickets[i] = 0u;             // cnt_b[128] + cnt2
    wbf[i] = f2bfu(W[i]);
    if (i < L_ * L_) {
        int r = i / L_, k = i - r * L_;       // etbf[r][k] = exp(trans[k][r])
        etbf[i] = f2bfu(__expf(trans[k * L_ + r]));
    }
}

// ---------- Kernel 2: fused GEMM + chunk product + gold partial + combine + reduce ----------
// Block i = (b = i>>3, c = i&7) -> rows i*32 .. i*32+31.
__global__ __launch_bounds__(256, 4) void fused_kernel(const float* __restrict__ x,
                                                       const unsigned short* __restrict__ wbf,
                                                       const float* __restrict__ bias,
                                                       const unsigned short* __restrict__ etbf,
                                                       const float* __restrict__ trans,
                                                       const int* __restrict__ tags,
                                                       const int* __restrict__ seq_len,
                                                       float* __restrict__ pred,
                                                       float* __restrict__ Xout,
                                                       float* __restrict__ lsc,
                                                       float* __restrict__ gsc,
                                                       float* __restrict__ res,
                                                       unsigned* __restrict__ tickets,
                                                       float* __restrict__ out) {
    __shared__ float red[2][64][12];   // 6 KB: K-split reduction
    __shared__ float elds[32 * L_];    // 6 KB: exp(pred) tile
    __shared__ float praw[32 * L_];    // 6 KB: raw pred tile (gold score)
    __shared__ float vb[64];           // combine broadcast
    const int wv = threadIdx.x >> 6;
    const int lane = threadIdx.x & 63;
    const int pair = wv >> 1;
    const int kh = wv & 1;
    const int m0 = blockIdx.x * 32 + pair * 16;
    const int l16 = lane & 15;
    const int lg  = lane >> 4;
    const int b = blockIdx.x >> 3, c = blockIdx.x & 7;
    const int n = seq_len[b];

    // ---- GEMM phase (R4/R8-proven) ----
    {
        const float* xrow = x + (size_t)(m0 + l16) * D_ + kh * 512 + lg * 8;
        const unsigned short* wrow = wbf + (size_t)l16 * D_ + kh * 512 + lg * 8;
        f32x4 acc0 = {0.f,0.f,0.f,0.f}, acc1 = {0.f,0.f,0.f,0.f}, acc2 = {0.f,0.f,0.f,0.f};

        #pragma unroll 8
        for (int k0 = 0; k0 < 512; k0 += 32) {
            float4 xa = *reinterpret_cast<const float4*>(xrow + k0);
            float4 xb = *reinterpret_cast<const float4*>(xrow + k0 + 4);
            u32x4 au;
            au[0] = cvt_pk_bf16(xa.x, xa.y);
            au[1] = cvt_pk_bf16(xa.z, xa.w);
            au[2] = cvt_pk_bf16(xb.x, xb.y);
            au[3] = cvt_pk_bf16(xb.z, xb.w);
            bf16x8 af = __builtin_bit_cast(bf16x8, au);
            const unsigned short* wp = wrow + k0;
            bf16x8 b0 = *reinterpret_cast<const bf16x8*>(wp);
            bf16x8 b1 = *reinterpret_cast<const bf16x8*>(wp + 16 * D_);
            bf16x8 b2 = *reinterpret_cast<const bf16x8*>(wp + 32 * D_);
            acc0 = __builtin_amdgcn_mfma_f32_16x16x32_bf16(af, b0, acc0, 0, 0, 0);
            acc1 = __builtin_amdgcn_mfma_f32_16x16x32_bf16(af, b1, acc1, 0, 0, 0);
            acc2 = __builtin_amdgcn_mfma_f32_16x16x32_bf16(af, b2, acc2, 0, 0, 0);
        }

        if (kh == 1) {
            #pragma unroll
            for (int r = 0; r < 4; ++r) {
                red[pair][lane][r]     = acc0[r];
                red[pair][lane][4 + r] = acc1[r];
                red[pair][lane][8 + r] = acc2[r];
            }
        }
        __syncthreads();
        if (kh == 0) {
            const int rbase = m0 + lg * 4;
            float bi0 = bias[l16], bi1 = bias[16 + l16], bi2 = bias[32 + l16];
            #pragma unroll
            for (int r = 0; r < 4; ++r) {
                size_t ro = (size_t)(rbase + r) * L_;
                float v0 = acc0[r] + red[pair][lane][r]     + bi0;
                float v1 = acc1[r] + red[pair][lane][4 + r] + bi1;
                float v2 = acc2[r] + red[pair][lane][8 + r] + bi2;
                pred[ro + l16]      = v0;
                pred[ro + 16 + l16] = v1;
                pred[ro + 32 + l16] = v2;
                int lrow = pair * 16 + lg * 4 + r;
                praw[lrow * L_ + l16]      = v0;
                praw[lrow * L_ + 16 + l16] = v1;
                praw[lrow * L_ + 32 + l16] = v2;
                elds[lrow * L_ + l16]      = __expf(v0);
                elds[lrow * L_ + 16 + l16] = __expf(v1);
                elds[lrow * L_ + 32 + l16] = (32 + l16 >= L_ - 2) ? 0.f : __expf(v2);
            }
        }
    }
    __syncthreads();

    if (wv == 1) {
        // ---- gold-path partial for rows [c*32, c*32+32) ----
        const int* tg = tags + b * T_;
        float s = 0.f;
        int t = c * 32 + lane;              // lanes 0..31 active
        if (lane < 32 && t < n) {
            int tag = tg[t];
            int pt = (t == 0) ? (L_ - 2) : tg[t - 1];
            s = praw[lane * L_ + tag] + trans[pt * L_ + tag];
            if (t == n - 1) s += trans[tag * L_ + (L_ - 1)];
        }
        #pragma unroll
        for (int o = 32; o > 0; o >>= 1) s += __shfl_xor(s, o, 64);
        if (lane == 0) gsc[blockIdx.x] = s;
    }

    if (wv == 0) {
        // ---- chunk product (R7/R8-proven) ----
        int nsteps = n - c * 32;
        nsteps = nsteps < 0 ? 0 : (nsteps > 32 ? 32 : nsteps);

        const int l15 = lane & 15, g = lane >> 4;
        bf16x4 A[3][3];
        #pragma unroll
        for (int mt = 0; mt < 3; ++mt)
            #pragma unroll
            for (int kt = 0; kt < 3; ++kt)
                A[mt][kt] = *reinterpret_cast<const bf16x4*>(etbf + (16 * mt + l15) * L_ + 16 * kt + 4 * g);

        f32x4 Cst[3][3];
        #pragma unroll
        for (int mt = 0; mt < 3; ++mt)
            #pragma unroll
            for (int nt = 0; nt < 3; ++nt)
                #pragma unroll
                for (int r = 0; r < 4; ++r)
                    Cst[mt][nt][r] = (mt == nt && 4 * g + r == l15) ? 1.f : 0.f;

        float lsum = 0.f;
        for (int q = 0; q < nsteps; ++q) {
            bf16x4 Bf[3][3];
            #pragma unroll
            for (int kt = 0; kt < 3; ++kt)
                #pragma unroll
                for (int nt = 0; nt < 3; ++nt)
                    Bf[kt][nt] = pack4(Cst[kt][nt][0], Cst[kt][nt][1], Cst[kt][nt][2], Cst[kt][nt][3]);

            f32x4 C[3][3];
            #pragma unroll
            for (int mt = 0; mt < 3; ++mt)
                #pragma unroll
                for (int nt = 0; nt < 3; ++nt)
                    C[mt][nt] = f32x4{0.f, 0.f, 0.f, 0.f};
            #pragma unroll
            for (int kt = 0; kt < 3; ++kt)
                #pragma unroll
                for (int mt = 0; mt < 3; ++mt)
                    #pragma unroll
                    for (int nt = 0; nt < 3; ++nt)
                        C[mt][nt] = mfma16(A[mt][kt], Bf[kt][nt], C[mt][nt]);

            float4 w0 = *reinterpret_cast<const float4*>(elds + q * L_ + 4 * g);
            float4 w1 = *reinterpret_cast<const float4*>(elds + q * L_ + 16 + 4 * g);
            float4 w2 = *reinterpret_cast<const float4*>(elds + q * L_ + 32 + 4 * g);

            float rn = 1.f;
            if ((q & 3) == 3) {
                float r = bcastf(C[0][0][0], 0);
                rn = __builtin_amdgcn_rcpf(r);
                lsum += __logf(r);
            }
            float sr[12];
            sr[0] = w0.x * rn; sr[1] = w0.y * rn; sr[2]  = w0.z * rn; sr[3]  = w0.w * rn;
            sr[4] = w1.x * rn; sr[5] = w1.y * rn; sr[6]  = w1.z * rn; sr[7]  = w1.w * rn;
            sr[8] = w2.x * rn; sr[9] = w2.y * rn; sr[10] = w2.z * rn; sr[11] = w2.w * rn;
            #pragma unroll
            for (int mt = 0; mt < 3; ++mt)
                #pragma unroll
                for (int nt = 0; nt < 3; ++nt)
                    #pragma unroll
                    for (int r = 0; r < 4; ++r)
                        Cst[mt][nt][r] = C[mt][nt][r] * sr[4 * mt + r];
        }

        float* xo = Xout + (size_t)blockIdx.x * 2304;
        #pragma unroll
        for (int mt = 0; mt < 3; ++mt)
            #pragma unroll
            for (int nt = 0; nt < 3; ++nt)
                #pragma unroll
                for (int r = 0; r < 4; ++r)
                    xo[(16 * mt + 4 * g + r) * L_ + 16 * nt + l15] = Cst[mt][nt][r];
        if (lane == 0) lsc[blockIdx.x] = lsum;
    }
    __syncthreads();          // gsc (wave1) + X/lsc (wave0) complete for this block
    if (wv != 0) return;

    // ---- per-batch ticket: 8th arriver combines batch b ----
    __threadfence();
    unsigned old = 0;
    if (lane == 0) old = atomicAdd(&tickets[b], 1u);
    old = __builtin_amdgcn_readlane(old, 0);
    if (old != 7) return;
    __threadfence();          // acquire: other blocks' X/lsc/gsc visible

    float sc_total = 0.f;
    #pragma unroll
    for (int cc = 0; cc < 8; ++cc) sc_total += gsc[b * 8 + cc];

    float v = (lane == L_ - 2) ? 1.f : 0.f;
    vb[lane] = v;
    float lsum = 0.f;
    #pragma unroll 1
    for (int cc = 0; cc < 8; ++cc) {
        const float* X = Xout + (size_t)(b * 8 + cc) * 2304;
        lsum += lsc[b * 8 + cc];
        float acc = 0.f;
        if (lane < L_) {
            const float4* vb4 = reinterpret_cast<const float4*>(vb);
            const float4* xr = reinterpret_cast<const float4*>(X + lane * L_);
            #pragma unroll
            for (int ci = 0; ci < 12; ++ci) {
                float4 xx = xr[ci];
                float4 vv = vb4[ci];
                acc = fmaf(xx.x, vv.x, acc);
                acc = fmaf(xx.y, vv.y, acc);
                acc = fmaf(xx.z, vv.z, acc);
                acc = fmaf(xx.w, vv.w, acc);
            }
        }
        float r = bcastf(acc, 0);          // alpha[0] > 0 always
        float rn = __builtin_amdgcn_rcpf(r);
        lsum += __logf(r);
        v = acc * rn;
        vb[lane] = (lane < L_) ? v : 0.f;
    }

    float term = (lane < L_) ? v * __expf(trans[lane * L_ + (L_ - 1)]) : 0.f;
    #pragma unroll
    for (int o = 32; o > 0; o >>= 1) term += __shfl_xor(term, o, 64);
    float logz = __logf(term) + lsum;

    if (lane == 0) res[b] = logz - sc_total;

    // ---- global ticket: 128th batch-combiner does the final reduce ----
    __threadfence();
    unsigned old2 = 0;
    if (lane == 0) old2 = atomicAdd(&tickets[B_], 1u);
    old2 = __builtin_amdgcn_readlane(old2, 0);
    if (old2 != B_ - 1) return;
    __threadfence();
    volatile const float* vr = res;
    float v2 = vr[lane] + vr[64 + lane];
    #pragma unroll
    for (int o = 32; o > 0; o >>= 1) v2 += __shfl_xor(v2, o, 64);
    if (lane == 0) out[0] = v2;
}

extern "C" void kernel_launch(void* const* d_in, const int* in_sizes, int n_in,
                              void* d_out, int out_size, void* d_ws, size_t ws_size,
                              hipStream_t stream) {
    const float* x      = (const float*)d_in[0];
    const float* W      = (const float*)d_in[1];
    const float* bias   = (const float*)d_in[2];
    const float* trans  = (const float*)d_in[3];
    const int*   tags   = (const int*)d_in[4];
    const int*   seqlen = (const int*)d_in[5];
    float* out = (float*)d_out;

    float* pred          = (float*)d_ws;                                   // 6291456 B
    unsigned short* wbf  = (unsigned short*)((char*)d_ws + 6291456);       // 98304 B
    unsigned short* etbf = (unsigned short*)((char*)d_ws + 6389760);       // 4608 B
    float* Xout          = (float*)((char*)d_ws + 6394368);                // 9437184 B
    float* lsc           = (float*)((char*)d_ws + 15831552);               // 4096 B
    float* res           = (float*)((char*)d_ws + 15835648);               // 512 B
    float* gsc           = (float*)((char*)d_ws + 15836160);               // 4096 B
    unsigned* tickets    = (unsigned*)((char*)d_ws + 15840256);            // 516 B
    
    hipLaunchKernelGGL(prep_kernel, dim3(192), dim3(256), 0, stream, W, trans, wbf, etbf, tickets);
    hipLaunchKernelGGL(fused_kernel, dim3(1024), dim3(256), 0, stream,
                       x, wbf, bias, etbf, trans, tags, seqlen,
                       pred, Xout, lsc, gsc, res, tickets, out);
}